// Round 6
// baseline (163.377 us; speedup 1.0000x reference)
//
#include <hip/hip_runtime.h>
#include <math.h>

#define T 4096
#define C 256
#define BATCH 2
#define NH 4
#define G 32
#define CPG 8
#define EPS 1e-5f
#define LOG2E 1.4426950408889634f
// Reference applies scale=ch^-0.25 to q AND k -> logit = (q.k)/8. Fold /8 and
// log2e (exp2-domain softmax) into Q once.
#define QSCALE (0.125f * LOG2E)
#define KSPLIT 8
#define KRANGE (T / KSPLIT)
#define KTILE 64
#define NIT (KRANGE / KTILE)
#define BH (BATCH * NH)

typedef __attribute__((ext_vector_type(8))) short bfv8;
typedef __attribute__((ext_vector_type(4))) short bfv4;
typedef __attribute__((ext_vector_type(4))) float f32x4;
typedef __attribute__((ext_vector_type(2))) float f32x2;
typedef __attribute__((ext_vector_type(16))) float f32x16;

static __device__ __forceinline__ short f2bf(float f) {
    union { float f; unsigned u; } v; v.f = f;
    return (short)((v.u + 0x7FFFu + ((v.u >> 16) & 1u)) >> 16);
}
static __device__ __forceinline__ float bf2f(short s) {
    union { float f; unsigned u; } v; v.u = ((unsigned)(unsigned short)s) << 16;
    return v.f;
}

#if __has_builtin(__builtin_amdgcn_exp2f)
#define EXP2(x) __builtin_amdgcn_exp2f(x)
#else
#define EXP2(x) exp2f(x)
#endif

#define AS1 __attribute__((address_space(1)))
#define AS3 __attribute__((address_space(3)))
static __device__ __forceinline__ void gll16(const void* g, void* l) {
    __builtin_amdgcn_global_load_lds((const AS1 void*)g, (AS3 void*)l, 16, 0, 0);
}

// ---------------------------------------------------------------------------
// Merged: weight prep (blocks 0..255) + GroupNorm stats (blocks 256..511).
// ---------------------------------------------------------------------------
__global__ __launch_bounds__(256) void prep_stats(
    const float* __restrict__ wq, const float* __restrict__ wp,
    short* __restrict__ wqb, short* __restrict__ wpb,
    const float* __restrict__ x, float* __restrict__ gnp)
{
    __shared__ float rs[256], rss[256];
    const int bid = blockIdx.x;
    const int tid = threadIdx.x;
    if (bid < 256) {
        int i = bid * 256 + tid;   // float4 index
        const int NQ = 768 * 256 / 4;
        float4 v; short* dst;
        if (i < NQ) { v = ((const float4*)wq)[i]; dst = wqb + i * 4; }
        else        { int j = i - NQ; v = ((const float4*)wp)[j]; dst = wpb + j * 4; }
        bfv4 o = { f2bf(v.x), f2bf(v.y), f2bf(v.z), f2bf(v.w) };
        *(bfv4*)dst = o;
        return;
    }
    const int blk = (bid - 256) >> 2;      // b*G+g
    const int ts  = (bid - 256) & 3;       // 0..3
    const int b = blk / G, g = blk % G;
    const float* xp = x + ((size_t)b * C + g * CPG) * T + ts * 1024;

    float s = 0.f, ss = 0.f;
    #pragma unroll
    for (int u = 0; u < CPG; u++) {
        float4 v = ((const float4*)(xp + (size_t)u * T))[tid];
        s  += v.x + v.y + v.z + v.w;
        ss += v.x*v.x + v.y*v.y + v.z*v.z + v.w*v.w;
    }
    rs[tid] = s; rss[tid] = ss;
    __syncthreads();
    for (int off = 128; off > 0; off >>= 1) {
        if (tid < off) { rs[tid] += rs[tid+off]; rss[tid] += rss[tid+off]; }
        __syncthreads();
    }
    if (tid == 0) {
        gnp[(blk * 4 + ts) * 2 + 0] = rs[0];
        gnp[(blk * 4 + ts) * 2 + 1] = rss[0];
    }
}

// ---------------------------------------------------------------------------
// GroupNorm normalize pass: grid (B*G, 4 t-splits), 256 thr -> bf16 xnT[b][t][c]
// ---------------------------------------------------------------------------
__global__ __launch_bounds__(256) void gn_norm(const float* __restrict__ x,
                                               const float* __restrict__ scale,
                                               const float* __restrict__ bias,
                                               const float* __restrict__ gnp,
                                               short* __restrict__ xnT) {
    const int blk = blockIdx.x;            // b*G+g
    const int ts  = blockIdx.y;            // 0..3
    const int b = blk / G, g = blk % G;
    const int c0 = g * CPG;
    const float* xp = x + ((size_t)b * C + c0) * T;

    float s = 0.f, ss = 0.f;
    #pragma unroll
    for (int i = 0; i < 4; i++) {
        s  += gnp[(blk * 4 + i) * 2 + 0];
        ss += gnp[(blk * 4 + i) * 2 + 1];
    }
    const float inv_n = 1.0f / (CPG * T);
    const float mu  = s * inv_n;
    const float var = ss * inv_n - mu * mu;
    const float rstd = rsqrtf(var + EPS);

    float sc[CPG], bi[CPG];
    #pragma unroll
    for (int u = 0; u < CPG; u++) {
        sc[u] = scale[c0+u] * rstd;
        bi[u] = bias[c0+u] - mu * sc[u];
    }

    const int t = ts * 1024 + threadIdx.x * 4;
    float vv[CPG][4];
    #pragma unroll
    for (int u = 0; u < CPG; u++) {
        float4 v = *(const float4*)&xp[(size_t)u * T + t];
        vv[u][0] = v.x * sc[u] + bi[u];
        vv[u][1] = v.y * sc[u] + bi[u];
        vv[u][2] = v.z * sc[u] + bi[u];
        vv[u][3] = v.w * sc[u] + bi[u];
    }
    #pragma unroll
    for (int j = 0; j < 4; j++) {
        bfv8 w = { f2bf(vv[0][j]), f2bf(vv[1][j]), f2bf(vv[2][j]), f2bf(vv[3][j]),
                   f2bf(vv[4][j]), f2bf(vv[5][j]), f2bf(vv[6][j]), f2bf(vv[7][j]) };
        *(bfv8*)&xnT[((size_t)b * T + t + j) * C + c0] = w;
    }
}

// ---------------------------------------------------------------------------
// qkv GEMM (bf16 MFMA, BK=64 — R9/R11/R13): grid (T/64, 12, BATCH), 256 thr.
// ---------------------------------------------------------------------------
__global__ __launch_bounds__(256) void gemm_qkv(
    const short* __restrict__ wq,    // [768][256] bf16
    const float* __restrict__ bq,    // [768]
    const short* __restrict__ xnT,   // [B][T][C] bf16
    short* __restrict__ qb, short* __restrict__ kb, short* __restrict__ vb)
{
    const int b  = blockIdx.z;
    const int t0 = blockIdx.x * 64;
    const int ot = blockIdx.y;
    const int h = ot / 3, part = ot % 3;
    const int o0 = ot * 64;

    __shared__ short sm[8192];       // A 8x512 + B 8x512 shorts (16 KiB)
    short* Ab = sm;
    short* Bb = sm + 4096;

    const int tid = threadIdx.x, lane = tid & 63, wave = tid >> 6;
    const int col = lane & 15, quad = lane >> 4;
    const short* xb = xnT + (size_t)b * T * C;

    f32x4 acc[4];
    #pragma unroll
    for (int g = 0; g < 4; g++) { acc[g][0]=0.f; acc[g][1]=0.f; acc[g][2]=0.f; acc[g][3]=0.f; }

    for (int k0 = 0; k0 < C; k0 += 64) {
        __syncthreads();
        #pragma unroll
        for (int hh = 0; hh < 2; hh++) {
            gll16(wq + (size_t)(o0 + 16*wave + col) * C + k0 + hh*32 + quad*8,
                  Ab + (hh*4 + wave) * 512);
            gll16(xb + (size_t)(t0 + 16*wave + col) * C + k0 + hh*32 + quad*8,
                  Bb + (hh*4 + wave) * 512);
        }
        __syncthreads();
        #pragma unroll
        for (int hh = 0; hh < 2; hh++) {
            bfv8 af = *(const bfv8*)(Ab + (hh*4 + wave) * 512 + lane*8);
            #pragma unroll
            for (int g = 0; g < 4; g++) {
                bfv8 bf = *(const bfv8*)(Bb + (hh*4 + g) * 512 + lane*8);
                acc[g] = __builtin_amdgcn_mfma_f32_16x16x32_bf16(af, bf, acc[g], 0, 0, 0);
            }
        }
    }

    const int olocal = 16*wave + quad*4;
    float bias_r[4];
    #pragma unroll
    for (int r = 0; r < 4; r++) bias_r[r] = bq[o0 + olocal + r];
    const size_t hd = (size_t)(b * NH + h);

    if (part < 2) {
        short* dst = (part == 0 ? qb : kb) + hd * T * 64;
        const float sc = (part == 0) ? QSCALE : 1.0f;
        #pragma unroll
        for (int g = 0; g < 4; g++) {
            int t = t0 + 16*g + col;
            bfv4 w = { f2bf((acc[g][0] + bias_r[0]) * sc),
                       f2bf((acc[g][1] + bias_r[1]) * sc),
                       f2bf((acc[g][2] + bias_r[2]) * sc),
                       f2bf((acc[g][3] + bias_r[3]) * sc) };
            *(bfv4*)&dst[(size_t)t * 64 + olocal] = w;
        }
    } else {
        short* dst = vb + hd * 64 * T;
        #pragma unroll
        for (int g = 0; g < 4; g++)
            #pragma unroll
            for (int r = 0; r < 4; r++)
                dst[(size_t)(olocal + r) * T + t0 + 16*g + col] =
                    f2bf(acc[g][r] + bias_r[r]);
    }
}

// ---------------------------------------------------------------------------
// Flash attention v13: v12's compute body (32x32x16 MFMA, cvt_pk P-pack,
// f32x2 lsum) at KTILE=64 (v11's proven 32KB staging/swizzle), with
// KSPLIT 4->8. R5 post-mortem: after cutting MFMA 35% and VALU 20%, wall
// moved only 2.5us -> stall-bound with 2 blocks/CU. R2 re-read: occupancy
// scaling WORKS (2x work in 1.17x time) but t-split doubles work. KSPLIT
// doubles blocks with ~zero extra work (staging/LDS/MFMA totals invariant;
// only Q-reload + opart epilogue double, both cache-absorbed). Grid
// (16,BH,8)=1024 = 4 blocks/CU (threads 2048/512, LDS 160/32, VGPR 60<=64).
// launch_bounds(512,4) NOT (512,8): forcing <=64 would spill (~78 live at
// PV peak incl accs); v12 measured 60 total with same body shape.
// K tile [64 key][64 ch], V tile [64 ch][64 key]; rows 8x16B chunks, XOR
// swizzle chunk^(row&7) staged via pre-swizzled global source (m173).
// ---------------------------------------------------------------------------
__global__ __launch_bounds__(512, 4) void attn_kernel(
    const short* __restrict__ qb,    // [BH][T][64] (pre-scaled by QSCALE)
    const short* __restrict__ kb,    // [BH][T][64]
    const short* __restrict__ vb,    // [BH][64][T]
    short* __restrict__ opart,       // [KSPLIT][BH][T][64] unnormalized O, bf16
    float* __restrict__ lp)          // [KSPLIT][BH][T]
{
    __shared__ short smem[16384];    // 2 x (K 8KB + V 8KB) = 32 KiB
    const int bh = blockIdx.y;
    const int ks = blockIdx.z;
    const int t0 = blockIdx.x * 256;
    const int k0base = ks * KRANGE;
    const short* kbh = kb + (size_t)bh * T * 64;
    const short* vbh = vb + (size_t)bh * 64 * T;

    const int tid  = threadIdx.x;
    const int lane = tid & 63;
    const int wave = tid >> 6;       // 0..7
    const int klow = lane & 31;      // m-index (key / ch) and n-index (query)
    const int hi   = lane >> 5;
    const int swz  = klow & 7;       // XOR-swizzle key (8 chunks/row)

    // Q B-frags: step s covers ch 16s..16s+15; slot (hi,j) -> ch 16s+8hi+j
    const int q = t0 + wave*32 + klow;
    const short* qrow = qb + (size_t)bh * T * 64 + (size_t)q * 64;
    bfv8 qf[4];
    #pragma unroll
    for (int s = 0; s < 4; s++) qf[s] = *(const bfv8*)(qrow + s*16 + hi*8);

    // O^T accumulators: tile c -> ch = 32c + (r&3)+8*(r>>2)+4hi, query = klow
    f32x16 oacc[2];
    #pragma unroll
    for (int c = 0; c < 2; c++)
        #pragma unroll
        for (int r = 0; r < 16; r++) oacc[c][r] = 0.f;
    f32x2 l2 = { 0.f, 0.f };

    // Staging: 512 lanes cover 64 rows x 8 chunks (16B each) per tile.
    // LDS dest linear (gll16); global source chunk XOR'd with row&7 so
    // LDS[row][chunk] = row[8*(chunk^(row&7))..] (involution, read side same).
    const int srow = wave*8 + (lane >> 3);    // key (K tile) / ch (V tile)
    const int schunk = lane & 7;
    #define STAGE_KV(buf, s0)                                                   \
        {                                                                       \
            short* base = smem + (buf) * 8192;                                  \
            gll16(kbh + (size_t)((s0) + srow) * 64 + ((schunk ^ (srow&7))<<3),  \
                  base + wave * 512);                                           \
            gll16(vbh + (size_t)srow * T + (s0) + ((schunk ^ (srow&7))<<3),     \
                  base + 4096 + wave * 512);                                    \
        }

    STAGE_KV(0, k0base)

    for (int it = 0; it < NIT; it++) {
        __syncthreads();                        // staged tile visible
        if (it + 1 < NIT) STAGE_KV((it+1) & 1, k0base + (it+1)*KTILE)

        const short* kvb = smem + (it & 1) * 8192;
        const short* kl = kvb + klow*64;                 // K row for this lane
        const short* vl = kvb + 4096 + klow*64 + 4*hi;   // V row base (+key 4hi)

        // Per 32-key sub-tile kt: S^T -> exp2 -> cvt_pk pack -> PV (kc=2kt+u)
        #pragma unroll
        for (int kt = 0; kt < 2; kt++) {
            f32x16 sacc;
            #pragma unroll
            for (int r = 0; r < 16; r++) sacc[r] = 0.f;
            #pragma unroll
            for (int s = 0; s < 4; s++) {
                bfv8 kf = *(const bfv8*)(kl + kt*2048 + (((2*s+hi) ^ swz) << 3));
                sacc = __builtin_amdgcn_mfma_f32_32x32x16_bf16(kf, qf[s], sacc, 0, 0, 0);
            }
            #pragma unroll
            for (int u = 0; u < 2; u++) {
                float p[8];
                #pragma unroll
                for (int j = 0; j < 8; j++) p[j] = EXP2(sacc[8*u + j]);
                f32x2 pa = { p[0], p[1] }, pb = { p[2], p[3] };
                f32x2 pc = { p[4], p[5] }, pd = { p[6], p[7] };
                l2 += (pa + pb) + (pc + pd);
                union { unsigned w[4]; bfv8 v; } pk_;
                #pragma unroll
                for (int w = 0; w < 4; w++)
                    asm("v_cvt_pk_bf16_f32 %0, %1, %2"
                        : "=v"(pk_.w[w]) : "v"(p[2*w]), "v"(p[2*w+1]));
                const int kc = 2*kt + u;    // keys kappa = 16kc+4hi+(j&3)+8*(j>>2)
                #pragma unroll
                for (int c = 0; c < 2; c++) {
                    bfv4 v0 = *(const bfv4*)(vl + c*2048 + (((2*kc)   ^ swz) << 3));
                    bfv4 v1 = *(const bfv4*)(vl + c*2048 + (((2*kc+1) ^ swz) << 3));
                    bfv8 vf = { v0[0], v0[1], v0[2], v0[3],
                                v1[0], v1[1], v1[2], v1[3] };
                    oacc[c] = __builtin_amdgcn_mfma_f32_32x32x16_bf16(
                                  vf, pk_.v, oacc[c], 0, 0, 0);
                }
            }
        }
    }

    // l: lane holds 32 of the 64 keys (its hi half) for query klow
    float lsum = l2[0] + l2[1];
    lsum += __shfl_xor(lsum, 32);

    // epilogue: lane owns t-row (t0+wave*32+klow); ch = 32c + 8u + 4hi + i
    const size_t rowbase = (size_t)(ks*BH + bh) * T + t0 + wave*32;
    short* opb = opart + (rowbase + klow) * 64;
    #pragma unroll
    for (int c = 0; c < 2; c++)
        #pragma unroll
        for (int u = 0; u < 4; u++) {
            bfv4 w = { f2bf(oacc[c][4*u+0]), f2bf(oacc[c][4*u+1]),
                       f2bf(oacc[c][4*u+2]), f2bf(oacc[c][4*u+3]) };
            *(bfv4*)(opb + c*32 + u*8 + hi*4) = w;
        }
    if (hi == 0) {
        lp[rowbase + klow] = lsum;
    }
}

// ---------------------------------------------------------------------------
// proj GEMM (bf16 MFMA, BK=64) with fused combine: B-operand built from
// opart (sum KSPLIT partials x per-head rl). + bias + fp32 resid.
// grid (T/64, 4, BATCH).
// ---------------------------------------------------------------------------
__global__ __launch_bounds__(256) void gemm_proj(
    const short* __restrict__ wp,    // [256][256] bf16
    const float* __restrict__ bp,    // [256]
    const short* __restrict__ opart, // [KSPLIT][BH][T][64] bf16
    const float* __restrict__ lp,    // [KSPLIT][BH][T]
    const float* __restrict__ x,     // [B][C][T] fp32 residual
    float* __restrict__ out)         // [B][C][T] fp32
{
    const int b  = blockIdx.z;
    const int t0 = blockIdx.x * 64;
    const int o0 = blockIdx.y * 64;

    __shared__ short sm[8192];       // A 8x512 + B 8x512 shorts (16 KiB)
    short* Ab = sm;
    short* Bb = sm + 4096;

    const int tid = threadIdx.x, lane = tid & 63, wave = tid >> 6;
    const int col = lane & 15, quad = lane >> 4;

    const int trow = t0 + 16*wave + col;
    float rl4[NH];
    #pragma unroll
    for (int hh = 0; hh < NH; hh++) {
        float ls = 0.f;
        #pragma unroll
        for (int ks = 0; ks < KSPLIT; ks++)
            ls += lp[((size_t)(ks*BH) + b*NH + hh) * T + trow];
        rl4[hh] = 1.0f / ls;
    }

    f32x4 acc[4];
    #pragma unroll
    for (int g = 0; g < 4; g++) { acc[g][0]=0.f; acc[g][1]=0.f; acc[g][2]=0.f; acc[g][3]=0.f; }

    for (int k0 = 0; k0 < C; k0 += 64) {
        __syncthreads();
        #pragma unroll
        for (int hh = 0; hh < 2; hh++) {
            gll16(wp + (size_t)(o0 + 16*wave + col) * C + k0 + hh*32 + quad*8,
                  Ab + (hh*4 + wave) * 512);
            const int chg = k0 + hh*32 + quad*8;       // global channel
            const int hd = chg >> 6, chin = chg & 63;  // hd is wave-uniform
            const short* ob = opart + (((size_t)(b*NH + hd)) * T + trow) * 64 + chin;
            float a8[8] = {0.f,0.f,0.f,0.f,0.f,0.f,0.f,0.f};
            #pragma unroll
            for (int ks = 0; ks < KSPLIT; ks++) {
                bfv8 v = *(const bfv8*)(ob + (size_t)ks * BH * T * 64);
                #pragma unroll
                for (int u = 0; u < 8; u++) a8[u] += bf2f(v[u]);
            }
            const float rl = rl4[hd];
            bfv8 pk;
            #pragma unroll
            for (int u = 0; u < 8; u++) pk[u] = f2bf(a8[u] * rl);
            *(bfv8*)(Bb + (hh*4 + wave) * 512 + lane*8) = pk;
        }
        __syncthreads();
        #pragma unroll
        for (int hh = 0; hh < 2; hh++) {
            bfv8 af = *(const bfv8*)(Ab + (hh*4 + wave) * 512 + lane*8);
            #pragma unroll
            for (int g = 0; g < 4; g++) {
                bfv8 bf = *(const bfv8*)(Bb + (hh*4 + g) * 512 + lane*8);
                acc[g] = __builtin_amdgcn_mfma_f32_16x16x32_bf16(af, bf, acc[g], 0, 0, 0);
            }
        }
    }

    const int olocal = 16*wave + quad*4;
    #pragma unroll
    for (int r = 0; r < 4; r++) {
        const int o = o0 + olocal + r;
        const float bias = bp[o];
        const size_t rowoff = ((size_t)b * C + o) * T;
        #pragma unroll
        for (int g = 0; g < 4; g++) {
            const size_t idx = rowoff + t0 + 16*g + col;
            out[idx] = acc[g][r] + bias + x[idx];
        }
    }
}

// ---------------------------------------------------------------------------
extern "C" void kernel_launch(void* const* d_in, const int* in_sizes, int n_in,
                              void* d_out, int out_size, void* d_ws, size_t ws_size,
                              hipStream_t stream) {
    (void)in_sizes; (void)n_in; (void)out_size; (void)ws_size;
    const float* x        = (const float*)d_in[0];
    const float* gn_scale = (const float*)d_in[1];
    const float* gn_bias  = (const float*)d_in[2];
    const float* w_qkv    = (const float*)d_in[3];
    const float* b_qkv    = (const float*)d_in[4];
    const float* w_proj   = (const float*)d_in[5];
    const float* b_proj   = (const float*)d_in[6];
    float* out = (float*)d_out;

    short* ws    = (short*)d_ws;
    short* qb    = ws;                                  // [BH][T][64]
    short* kb    = qb  + (size_t)BH * T * 64;
    short* vb    = kb  + (size_t)BH * T * 64;
    short* xnT   = vb  + (size_t)BH * T * 64;           // [B][T][C]
    short* wqb   = xnT + (size_t)BATCH * T * C;
    short* wpb   = wqb + 768 * 256;
    short* opart = wpb + 256 * 256;                     // [KSPLIT][BH][T][64] bf16
    float* lp    = (float*)(opart + (size_t)KSPLIT * BH * T * 64);  // [KSPLIT][BH][T]
    float* gnp   = lp + (size_t)KSPLIT * BH * T;        // [64][4][2]

    prep_stats<<<dim3(512), 256, 0, stream>>>(w_qkv, w_proj, wqb, wpb, x, gnp);
    gn_norm<<<dim3(BATCH * G, 4), 256, 0, stream>>>(x, gn_scale, gn_bias, gnp, xnT);
    gemm_qkv<<<dim3(T/64, 12, BATCH), 256, 0, stream>>>(wqb, b_qkv, xnT, qb, kb, vb);
    attn_kernel<<<dim3(T/256, BH, KSPLIT), 512, 0, stream>>>(qb, kb, vb, opart, lp);
    gemm_proj<<<dim3(T/64, 4, BATCH), 256, 0, stream>>>(wpb, b_proj, opart, lp, x, out);
}

// Round 7
// 149.389 us; speedup vs baseline: 1.0936x; 1.0936x over previous
//
#include <hip/hip_runtime.h>
#include <math.h>

#define T 4096
#define C 256
#define BATCH 2
#define NH 4
#define G 32
#define CPG 8
#define EPS 1e-5f
#define LOG2E 1.4426950408889634f
// Reference applies scale=ch^-0.25 to q AND k -> logit = (q.k)/8. Fold /8 and
// log2e (exp2-domain softmax) into Q once.
#define QSCALE (0.125f * LOG2E)
#define KSPLIT 4
#define KRANGE (T / KSPLIT)
#define KTILE 128
#define NIT (KRANGE / KTILE)
#define BH (BATCH * NH)

typedef __attribute__((ext_vector_type(8))) short bfv8;
typedef __attribute__((ext_vector_type(4))) short bfv4;
typedef __attribute__((ext_vector_type(4))) float f32x4;
typedef __attribute__((ext_vector_type(2))) float f32x2;
typedef __attribute__((ext_vector_type(16))) float f32x16;

static __device__ __forceinline__ short f2bf(float f) {
    union { float f; unsigned u; } v; v.f = f;
    return (short)((v.u + 0x7FFFu + ((v.u >> 16) & 1u)) >> 16);
}
static __device__ __forceinline__ float bf2f(short s) {
    union { float f; unsigned u; } v; v.u = ((unsigned)(unsigned short)s) << 16;
    return v.f;
}

#if __has_builtin(__builtin_amdgcn_exp2f)
#define EXP2(x) __builtin_amdgcn_exp2f(x)
#else
#define EXP2(x) exp2f(x)
#endif

#define AS1 __attribute__((address_space(1)))
#define AS3 __attribute__((address_space(3)))
static __device__ __forceinline__ void gll16(const void* g, void* l) {
    __builtin_amdgcn_global_load_lds((const AS1 void*)g, (AS3 void*)l, 16, 0, 0);
}

// ---------------------------------------------------------------------------
// Merged: weight prep (blocks 0..255) + GroupNorm stats (blocks 256..511).
// ---------------------------------------------------------------------------
__global__ __launch_bounds__(256) void prep_stats(
    const float* __restrict__ wq, const float* __restrict__ wp,
    short* __restrict__ wqb, short* __restrict__ wpb,
    const float* __restrict__ x, float* __restrict__ gnp)
{
    __shared__ float rs[256], rss[256];
    const int bid = blockIdx.x;
    const int tid = threadIdx.x;
    if (bid < 256) {
        int i = bid * 256 + tid;   // float4 index
        const int NQ = 768 * 256 / 4;
        float4 v; short* dst;
        if (i < NQ) { v = ((const float4*)wq)[i]; dst = wqb + i * 4; }
        else        { int j = i - NQ; v = ((const float4*)wp)[j]; dst = wpb + j * 4; }
        bfv4 o = { f2bf(v.x), f2bf(v.y), f2bf(v.z), f2bf(v.w) };
        *(bfv4*)dst = o;
        return;
    }
    const int blk = (bid - 256) >> 2;      // b*G+g
    const int ts  = (bid - 256) & 3;       // 0..3
    const int b = blk / G, g = blk % G;
    const float* xp = x + ((size_t)b * C + g * CPG) * T + ts * 1024;

    float s = 0.f, ss = 0.f;
    #pragma unroll
    for (int u = 0; u < CPG; u++) {
        float4 v = ((const float4*)(xp + (size_t)u * T))[tid];
        s  += v.x + v.y + v.z + v.w;
        ss += v.x*v.x + v.y*v.y + v.z*v.z + v.w*v.w;
    }
    rs[tid] = s; rss[tid] = ss;
    __syncthreads();
    for (int off = 128; off > 0; off >>= 1) {
        if (tid < off) { rs[tid] += rs[tid+off]; rss[tid] += rss[tid+off]; }
        __syncthreads();
    }
    if (tid == 0) {
        gnp[(blk * 4 + ts) * 2 + 0] = rs[0];
        gnp[(blk * 4 + ts) * 2 + 1] = rss[0];
    }
}

// ---------------------------------------------------------------------------
// GroupNorm normalize pass: grid (B*G, 4 t-splits), 256 thr -> bf16 xnT[b][t][c]
// ---------------------------------------------------------------------------
__global__ __launch_bounds__(256) void gn_norm(const float* __restrict__ x,
                                               const float* __restrict__ scale,
                                               const float* __restrict__ bias,
                                               const float* __restrict__ gnp,
                                               short* __restrict__ xnT) {
    const int blk = blockIdx.x;            // b*G+g
    const int ts  = blockIdx.y;            // 0..3
    const int b = blk / G, g = blk % G;
    const int c0 = g * CPG;
    const float* xp = x + ((size_t)b * C + c0) * T;

    float s = 0.f, ss = 0.f;
    #pragma unroll
    for (int i = 0; i < 4; i++) {
        s  += gnp[(blk * 4 + i) * 2 + 0];
        ss += gnp[(blk * 4 + i) * 2 + 1];
    }
    const float inv_n = 1.0f / (CPG * T);
    const float mu  = s * inv_n;
    const float var = ss * inv_n - mu * mu;
    const float rstd = rsqrtf(var + EPS);

    float sc[CPG], bi[CPG];
    #pragma unroll
    for (int u = 0; u < CPG; u++) {
        sc[u] = scale[c0+u] * rstd;
        bi[u] = bias[c0+u] - mu * sc[u];
    }

    const int t = ts * 1024 + threadIdx.x * 4;
    float vv[CPG][4];
    #pragma unroll
    for (int u = 0; u < CPG; u++) {
        float4 v = *(const float4*)&xp[(size_t)u * T + t];
        vv[u][0] = v.x * sc[u] + bi[u];
        vv[u][1] = v.y * sc[u] + bi[u];
        vv[u][2] = v.z * sc[u] + bi[u];
        vv[u][3] = v.w * sc[u] + bi[u];
    }
    #pragma unroll
    for (int j = 0; j < 4; j++) {
        bfv8 w = { f2bf(vv[0][j]), f2bf(vv[1][j]), f2bf(vv[2][j]), f2bf(vv[3][j]),
                   f2bf(vv[4][j]), f2bf(vv[5][j]), f2bf(vv[6][j]), f2bf(vv[7][j]) };
        *(bfv8*)&xnT[((size_t)b * T + t + j) * C + c0] = w;
    }
}

// ---------------------------------------------------------------------------
// qkv GEMM (bf16 MFMA, BK=64 — R9/R11/R13): grid (T/64, 12, BATCH), 256 thr.
// ---------------------------------------------------------------------------
__global__ __launch_bounds__(256) void gemm_qkv(
    const short* __restrict__ wq,    // [768][256] bf16
    const float* __restrict__ bq,    // [768]
    const short* __restrict__ xnT,   // [B][T][C] bf16
    short* __restrict__ qb, short* __restrict__ kb, short* __restrict__ vb)
{
    const int b  = blockIdx.z;
    const int t0 = blockIdx.x * 64;
    const int ot = blockIdx.y;
    const int h = ot / 3, part = ot % 3;
    const int o0 = ot * 64;

    __shared__ short sm[8192];       // A 8x512 + B 8x512 shorts (16 KiB)
    short* Ab = sm;
    short* Bb = sm + 4096;

    const int tid = threadIdx.x, lane = tid & 63, wave = tid >> 6;
    const int col = lane & 15, quad = lane >> 4;
    const short* xb = xnT + (size_t)b * T * C;

    f32x4 acc[4];
    #pragma unroll
    for (int g = 0; g < 4; g++) { acc[g][0]=0.f; acc[g][1]=0.f; acc[g][2]=0.f; acc[g][3]=0.f; }

    for (int k0 = 0; k0 < C; k0 += 64) {
        __syncthreads();
        #pragma unroll
        for (int hh = 0; hh < 2; hh++) {
            gll16(wq + (size_t)(o0 + 16*wave + col) * C + k0 + hh*32 + quad*8,
                  Ab + (hh*4 + wave) * 512);
            gll16(xb + (size_t)(t0 + 16*wave + col) * C + k0 + hh*32 + quad*8,
                  Bb + (hh*4 + wave) * 512);
        }
        __syncthreads();
        #pragma unroll
        for (int hh = 0; hh < 2; hh++) {
            bfv8 af = *(const bfv8*)(Ab + (hh*4 + wave) * 512 + lane*8);
            #pragma unroll
            for (int g = 0; g < 4; g++) {
                bfv8 bf = *(const bfv8*)(Bb + (hh*4 + g) * 512 + lane*8);
                acc[g] = __builtin_amdgcn_mfma_f32_16x16x32_bf16(af, bf, acc[g], 0, 0, 0);
            }
        }
    }

    const int olocal = 16*wave + quad*4;
    float bias_r[4];
    #pragma unroll
    for (int r = 0; r < 4; r++) bias_r[r] = bq[o0 + olocal + r];
    const size_t hd = (size_t)(b * NH + h);

    if (part < 2) {
        short* dst = (part == 0 ? qb : kb) + hd * T * 64;
        const float sc = (part == 0) ? QSCALE : 1.0f;
        #pragma unroll
        for (int g = 0; g < 4; g++) {
            int t = t0 + 16*g + col;
            bfv4 w = { f2bf((acc[g][0] + bias_r[0]) * sc),
                       f2bf((acc[g][1] + bias_r[1]) * sc),
                       f2bf((acc[g][2] + bias_r[2]) * sc),
                       f2bf((acc[g][3] + bias_r[3]) * sc) };
            *(bfv4*)&dst[(size_t)t * 64 + olocal] = w;
        }
    } else {
        short* dst = vb + hd * 64 * T;
        #pragma unroll
        for (int g = 0; g < 4; g++)
            #pragma unroll
            for (int r = 0; r < 4; r++)
                dst[(size_t)(olocal + r) * T + t0 + 16*g + col] =
                    f2bf(acc[g][r] + bias_r[r]);
    }
}

// ---------------------------------------------------------------------------
// Flash attention v14: v12's body (best measured: 47.0us) + T1 XCD swizzle.
// R6 diagnosis: (1) unified-file VGPR+AGPR ~128/wave caps residency at 2
// blocks/CU regardless of grid (R6 null); (2) FETCH_SIZE 34.9MB vs ~12MB
// cold-read ideal -> per-XCD L2 thrash: default round-robin puts all 8
// heads' K/V (8MB) in every 4MB XCD L2, so staging gll16s run at HBM
// latency (~900cy) which 4 waves/SIMD cannot hide. Fix: flat 1-D grid with
// bh = blockid & 7 -> all 64 blocks of a head land on one XCD (round-robin
// dispatch), whose L2 then holds just that head's 1MB K/V. Zero work change.
// K tile [128 key][64 ch] rows 8x16B chunks, swz key row&7 = klow&7.
// V tile [64 ch][128 key] rows 16x16B chunks, swz key row&15 = klow&15.
// Both staged with pre-swizzled global source (m173), read with same XOR.
// ---------------------------------------------------------------------------
__global__ __launch_bounds__(512, 4) void attn_kernel(
    const short* __restrict__ qb,    // [BH][T][64] (pre-scaled by QSCALE)
    const short* __restrict__ kb,    // [BH][T][64]
    const short* __restrict__ vb,    // [BH][64][T]
    short* __restrict__ opart,       // [KSPLIT][BH][T][64] unnormalized O, bf16
    float* __restrict__ lp)          // [KSPLIT][BH][T]
{
    __shared__ short smem[32768];    // 2 x (K 16KB + V 16KB) = 64 KiB
    // T1 relabel: flat id -> (bh, tb, ks) with bh = id&7 so each head's
    // blocks share an XCD (and its L2 copy of that head's K/V).
    const int flat = blockIdx.x;             // 0..511
    const int bh = flat & 7;
    const int tb = (flat >> 3) & 15;
    const int ks = flat >> 7;
    const int t0 = tb * 256;
    const int k0base = ks * KRANGE;
    const short* kbh = kb + (size_t)bh * T * 64;
    const short* vbh = vb + (size_t)bh * 64 * T;

    const int tid  = threadIdx.x;
    const int lane = tid & 63;
    const int wave = tid >> 6;       // 0..7
    const int klow = lane & 31;      // m-index (key / ch) and n-index (query)
    const int hi   = lane >> 5;
    const int swz  = klow & 7;       // K-tile XOR key (8 chunks/row)
    const int vswz = klow & 15;      // V-tile XOR key (16 chunks/row)

    // Q B-frags: step s covers ch 16s..16s+15; slot (hi,j) -> ch 16s+8hi+j
    const int q = t0 + wave*32 + klow;
    const short* qrow = qb + (size_t)bh * T * 64 + (size_t)q * 64;
    bfv8 qf[4];
    #pragma unroll
    for (int s = 0; s < 4; s++) qf[s] = *(const bfv8*)(qrow + s*16 + hi*8);

    // O^T accumulators: tile c -> ch = 32c + (r&3)+8*(r>>2)+4hi, query = klow
    f32x16 oacc[2];
    #pragma unroll
    for (int c = 0; c < 2; c++)
        #pragma unroll
        for (int r = 0; r < 16; r++) oacc[c][r] = 0.f;
    f32x2 l2 = { 0.f, 0.f };

    // Staging: per buffer, K = 1024 chunks (128 rows x 8), V = 1024 chunks
    // (64 rows x 16). Each wave issues 2 K + 2 V gll16 (lane covers 16B).
    // LDS dest linear; global source chunk XOR'd with row's swizzle key.
    const int lr8  = lane >> 3, lc8  = lane & 7;    // K staging row-sub/chunk
    const int lr16 = lane >> 4, lc16 = lane & 15;   // V staging row-sub/chunk
    #define STAGE_KV(buf, s0)                                                   \
        {                                                                       \
            short* base = smem + (buf) * 16384;                                 \
            const int r0 = (wave*2+0)*8 + lr8;                                  \
            const int r1 = (wave*2+1)*8 + lr8;                                  \
            gll16(kbh + (size_t)((s0) + r0) * 64 + ((lc8 ^ (r0&7))<<3),         \
                  base + (wave*2+0)*512);                                       \
            gll16(kbh + (size_t)((s0) + r1) * 64 + ((lc8 ^ (r1&7))<<3),         \
                  base + (wave*2+1)*512);                                       \
            const int v0r = (wave*2+0)*4 + lr16;                                \
            const int v1r = (wave*2+1)*4 + lr16;                                \
            gll16(vbh + (size_t)v0r * T + (s0) + ((lc16 ^ (v0r&15))<<3),        \
                  base + 8192 + (wave*2+0)*512);                                \
            gll16(vbh + (size_t)v1r * T + (s0) + ((lc16 ^ (v1r&15))<<3),        \
                  base + 8192 + (wave*2+1)*512);                                \
        }

    STAGE_KV(0, k0base)

    for (int it = 0; it < NIT; it++) {
        __syncthreads();                        // staged tile visible
        if (it + 1 < NIT) STAGE_KV((it+1) & 1, k0base + (it+1)*KTILE)

        const short* kvb = smem + (it & 1) * 16384;
        const short* kl = kvb + klow*64;                   // K row for this lane
        const short* vl = kvb + 8192 + klow*128 + 4*hi;    // V row base (+key 4hi)

        // Per 32-key sub-tile kt: S^T -> exp2 -> cvt_pk pack -> PV (kc=2kt+u)
        #pragma unroll
        for (int kt = 0; kt < 4; kt++) {
            f32x16 sacc;
            #pragma unroll
            for (int r = 0; r < 16; r++) sacc[r] = 0.f;
            #pragma unroll
            for (int s = 0; s < 4; s++) {
                bfv8 kf = *(const bfv8*)(kl + kt*2048 + (((2*s+hi) ^ swz) << 3));
                sacc = __builtin_amdgcn_mfma_f32_32x32x16_bf16(kf, qf[s], sacc, 0, 0, 0);
            }
            #pragma unroll
            for (int u = 0; u < 2; u++) {
                float p[8];
                #pragma unroll
                for (int j = 0; j < 8; j++) p[j] = EXP2(sacc[8*u + j]);
                f32x2 pa = { p[0], p[1] }, pb = { p[2], p[3] };
                f32x2 pc = { p[4], p[5] }, pd = { p[6], p[7] };
                l2 += (pa + pb) + (pc + pd);
                union { unsigned w[4]; bfv8 v; } pk_;
                #pragma unroll
                for (int w = 0; w < 4; w++)
                    asm("v_cvt_pk_bf16_f32 %0, %1, %2"
                        : "=v"(pk_.w[w]) : "v"(p[2*w]), "v"(p[2*w+1]));
                const int kc = 2*kt + u;    // keys kappa = 16kc+4hi+(j&3)+8*(j>>2)
                #pragma unroll
                for (int c = 0; c < 2; c++) {
                    bfv4 v0 = *(const bfv4*)(vl + c*4096 + (((2*kc)   ^ vswz) << 3));
                    bfv4 v1 = *(const bfv4*)(vl + c*4096 + (((2*kc+1) ^ vswz) << 3));
                    bfv8 vf = { v0[0], v0[1], v0[2], v0[3],
                                v1[0], v1[1], v1[2], v1[3] };
                    oacc[c] = __builtin_amdgcn_mfma_f32_32x32x16_bf16(
                                  vf, pk_.v, oacc[c], 0, 0, 0);
                }
            }
        }
    }

    // l: lane holds 32 of the 64 keys (its hi half) for query klow
    float lsum = l2[0] + l2[1];
    lsum += __shfl_xor(lsum, 32);

    // epilogue: lane owns t-row (t0+wave*32+klow); ch = 32c + 8u + 4hi + i
    const size_t rowbase = (size_t)(ks*BH + bh) * T + t0 + wave*32;
    short* opb = opart + (rowbase + klow) * 64;
    #pragma unroll
    for (int c = 0; c < 2; c++)
        #pragma unroll
        for (int u = 0; u < 4; u++) {
            bfv4 w = { f2bf(oacc[c][4*u+0]), f2bf(oacc[c][4*u+1]),
                       f2bf(oacc[c][4*u+2]), f2bf(oacc[c][4*u+3]) };
            *(bfv4*)(opb + c*32 + u*8 + hi*4) = w;
        }
    if (hi == 0) {
        lp[rowbase + klow] = lsum;
    }
}

// ---------------------------------------------------------------------------
// proj GEMM (bf16 MFMA, BK=64) with fused combine: B-operand built from
// opart (sum KSPLIT partials x per-head rl). + bias + fp32 resid.
// grid (T/64, 4, BATCH).
// ---------------------------------------------------------------------------
__global__ __launch_bounds__(256) void gemm_proj(
    const short* __restrict__ wp,    // [256][256] bf16
    const float* __restrict__ bp,    // [256]
    const short* __restrict__ opart, // [KSPLIT][BH][T][64] bf16
    const float* __restrict__ lp,    // [KSPLIT][BH][T]
    const float* __restrict__ x,     // [B][C][T] fp32 residual
    float* __restrict__ out)         // [B][C][T] fp32
{
    const int b  = blockIdx.z;
    const int t0 = blockIdx.x * 64;
    const int o0 = blockIdx.y * 64;

    __shared__ short sm[8192];       // A 8x512 + B 8x512 shorts (16 KiB)
    short* Ab = sm;
    short* Bb = sm + 4096;

    const int tid = threadIdx.x, lane = tid & 63, wave = tid >> 6;
    const int col = lane & 15, quad = lane >> 4;

    const int trow = t0 + 16*wave + col;
    float rl4[NH];
    #pragma unroll
    for (int hh = 0; hh < NH; hh++) {
        float ls = 0.f;
        #pragma unroll
        for (int ks = 0; ks < KSPLIT; ks++)
            ls += lp[((size_t)(ks*BH) + b*NH + hh) * T + trow];
        rl4[hh] = 1.0f / ls;
    }

    f32x4 acc[4];
    #pragma unroll
    for (int g = 0; g < 4; g++) { acc[g][0]=0.f; acc[g][1]=0.f; acc[g][2]=0.f; acc[g][3]=0.f; }

    for (int k0 = 0; k0 < C; k0 += 64) {
        __syncthreads();
        #pragma unroll
        for (int hh = 0; hh < 2; hh++) {
            gll16(wp + (size_t)(o0 + 16*wave + col) * C + k0 + hh*32 + quad*8,
                  Ab + (hh*4 + wave) * 512);
            const int chg = k0 + hh*32 + quad*8;       // global channel
            const int hd = chg >> 6, chin = chg & 63;  // hd is wave-uniform
            const short* ob = opart + (((size_t)(b*NH + hd)) * T + trow) * 64 + chin;
            float a8[8] = {0.f,0.f,0.f,0.f,0.f,0.f,0.f,0.f};
            #pragma unroll
            for (int ks = 0; ks < KSPLIT; ks++) {
                bfv8 v = *(const bfv8*)(ob + (size_t)ks * BH * T * 64);
                #pragma unroll
                for (int u = 0; u < 8; u++) a8[u] += bf2f(v[u]);
            }
            const float rl = rl4[hd];
            bfv8 pk;
            #pragma unroll
            for (int u = 0; u < 8; u++) pk[u] = f2bf(a8[u] * rl);
            *(bfv8*)(Bb + (hh*4 + wave) * 512 + lane*8) = pk;
        }
        __syncthreads();
        #pragma unroll
        for (int hh = 0; hh < 2; hh++) {
            bfv8 af = *(const bfv8*)(Ab + (hh*4 + wave) * 512 + lane*8);
            #pragma unroll
            for (int g = 0; g < 4; g++) {
                bfv8 bf = *(const bfv8*)(Bb + (hh*4 + g) * 512 + lane*8);
                acc[g] = __builtin_amdgcn_mfma_f32_16x16x32_bf16(af, bf, acc[g], 0, 0, 0);
            }
        }
    }

    const int olocal = 16*wave + quad*4;
    #pragma unroll
    for (int r = 0; r < 4; r++) {
        const int o = o0 + olocal + r;
        const float bias = bp[o];
        const size_t rowoff = ((size_t)b * C + o) * T;
        #pragma unroll
        for (int g = 0; g < 4; g++) {
            const size_t idx = rowoff + t0 + 16*g + col;
            out[idx] = acc[g][r] + bias + x[idx];
        }
    }
}

// ---------------------------------------------------------------------------
extern "C" void kernel_launch(void* const* d_in, const int* in_sizes, int n_in,
                              void* d_out, int out_size, void* d_ws, size_t ws_size,
                              hipStream_t stream) {
    (void)in_sizes; (void)n_in; (void)out_size; (void)ws_size;
    const float* x        = (const float*)d_in[0];
    const float* gn_scale = (const float*)d_in[1];
    const float* gn_bias  = (const float*)d_in[2];
    const float* w_qkv    = (const float*)d_in[3];
    const float* b_qkv    = (const float*)d_in[4];
    const float* w_proj   = (const float*)d_in[5];
    const float* b_proj   = (const float*)d_in[6];
    float* out = (float*)d_out;

    short* ws    = (short*)d_ws;
    short* qb    = ws;                                  // [BH][T][64]
    short* kb    = qb  + (size_t)BH * T * 64;
    short* vb    = kb  + (size_t)BH * T * 64;
    short* xnT   = vb  + (size_t)BH * T * 64;           // [B][T][C]
    short* wqb   = xnT + (size_t)BATCH * T * C;
    short* wpb   = wqb + 768 * 256;
    short* opart = wpb + 256 * 256;                     // [KSPLIT][BH][T][64] bf16
    float* lp    = (float*)(opart + (size_t)KSPLIT * BH * T * 64);  // [KSPLIT][BH][T]
    float* gnp   = lp + (size_t)KSPLIT * BH * T;        // [64][4][2]

    prep_stats<<<dim3(512), 256, 0, stream>>>(w_qkv, w_proj, wqb, wpb, x, gnp);
    gn_norm<<<dim3(BATCH * G, 4), 256, 0, stream>>>(x, gn_scale, gn_bias, gnp, xnT);
    gemm_qkv<<<dim3(T/64, 12, BATCH), 256, 0, stream>>>(wqb, b_qkv, xnT, qb, kb, vb);
    attn_kernel<<<dim3(512), 512, 0, stream>>>(qb, kb, vb, opart, lp);
    gemm_proj<<<dim3(T/64, 4, BATCH), 256, 0, stream>>>(wpb, b_proj, opart, lp, x, out);
}

// Round 9
// 146.553 us; speedup vs baseline: 1.1148x; 1.0193x over previous
//
#include <hip/hip_runtime.h>
#include <math.h>

#define T 4096
#define C 256
#define BATCH 2
#define NH 4
#define G 32
#define CPG 8
#define EPS 1e-5f
#define LOG2E 1.4426950408889634f
// Reference applies scale=ch^-0.25 to q AND k -> logit = (q.k)/8. Fold /8 and
// log2e (exp2-domain softmax) into Q once.
#define QSCALE (0.125f * LOG2E)
#define KSPLIT 4
#define KRANGE (T / KSPLIT)
#define KTILE 128
#define NIT (KRANGE / KTILE)
#define BH (BATCH * NH)

typedef __attribute__((ext_vector_type(8))) short bfv8;
typedef __attribute__((ext_vector_type(4))) short bfv4;
typedef __attribute__((ext_vector_type(4))) float f32x4;
typedef __attribute__((ext_vector_type(2))) float f32x2;
typedef __attribute__((ext_vector_type(16))) float f32x16;

static __device__ __forceinline__ short f2bf(float f) {
    union { float f; unsigned u; } v; v.f = f;
    return (short)((v.u + 0x7FFFu + ((v.u >> 16) & 1u)) >> 16);
}
static __device__ __forceinline__ float bf2f(short s) {
    union { float f; unsigned u; } v; v.u = ((unsigned)(unsigned short)s) << 16;
    return v.f;
}

#if __has_builtin(__builtin_amdgcn_exp2f)
#define EXP2(x) __builtin_amdgcn_exp2f(x)
#else
#define EXP2(x) exp2f(x)
#endif

#define AS1 __attribute__((address_space(1)))
#define AS3 __attribute__((address_space(3)))
static __device__ __forceinline__ void gll16(const void* g, void* l) {
    __builtin_amdgcn_global_load_lds((const AS1 void*)g, (AS3 void*)l, 16, 0, 0);
}

// ---------------------------------------------------------------------------
// Merged: weight prep (blocks 0..255) + GroupNorm stats (blocks 256..511).
// ---------------------------------------------------------------------------
__global__ __launch_bounds__(256) void prep_stats(
    const float* __restrict__ wq, const float* __restrict__ wp,
    short* __restrict__ wqb, short* __restrict__ wpb,
    const float* __restrict__ x, float* __restrict__ gnp)
{
    __shared__ float rs[256], rss[256];
    const int bid = blockIdx.x;
    const int tid = threadIdx.x;
    if (bid < 256) {
        int i = bid * 256 + tid;   // float4 index
        const int NQ = 768 * 256 / 4;
        float4 v; short* dst;
        if (i < NQ) { v = ((const float4*)wq)[i]; dst = wqb + i * 4; }
        else        { int j = i - NQ; v = ((const float4*)wp)[j]; dst = wpb + j * 4; }
        bfv4 o = { f2bf(v.x), f2bf(v.y), f2bf(v.z), f2bf(v.w) };
        *(bfv4*)dst = o;
        return;
    }
    const int blk = (bid - 256) >> 2;      // b*G+g
    const int ts  = (bid - 256) & 3;       // 0..3
    const int b = blk / G, g = blk % G;
    const float* xp = x + ((size_t)b * C + g * CPG) * T + ts * 1024;

    float s = 0.f, ss = 0.f;
    #pragma unroll
    for (int u = 0; u < CPG; u++) {
        float4 v = ((const float4*)(xp + (size_t)u * T))[tid];
        s  += v.x + v.y + v.z + v.w;
        ss += v.x*v.x + v.y*v.y + v.z*v.z + v.w*v.w;
    }
    rs[tid] = s; rss[tid] = ss;
    __syncthreads();
    for (int off = 128; off > 0; off >>= 1) {
        if (tid < off) { rs[tid] += rs[tid+off]; rss[tid] += rss[tid+off]; }
        __syncthreads();
    }
    if (tid == 0) {
        gnp[(blk * 4 + ts) * 2 + 0] = rs[0];
        gnp[(blk * 4 + ts) * 2 + 1] = rss[0];
    }
}

// ---------------------------------------------------------------------------
// GroupNorm normalize pass: grid (B*G, 4 t-splits), 256 thr -> bf16 xnT[b][t][c]
// ---------------------------------------------------------------------------
__global__ __launch_bounds__(256) void gn_norm(const float* __restrict__ x,
                                               const float* __restrict__ scale,
                                               const float* __restrict__ bias,
                                               const float* __restrict__ gnp,
                                               short* __restrict__ xnT) {
    const int blk = blockIdx.x;            // b*G+g
    const int ts  = blockIdx.y;            // 0..3
    const int b = blk / G, g = blk % G;
    const int c0 = g * CPG;
    const float* xp = x + ((size_t)b * C + c0) * T;

    float s = 0.f, ss = 0.f;
    #pragma unroll
    for (int i = 0; i < 4; i++) {
        s  += gnp[(blk * 4 + i) * 2 + 0];
        ss += gnp[(blk * 4 + i) * 2 + 1];
    }
    const float inv_n = 1.0f / (CPG * T);
    const float mu  = s * inv_n;
    const float var = ss * inv_n - mu * mu;
    const float rstd = rsqrtf(var + EPS);

    float sc[CPG], bi[CPG];
    #pragma unroll
    for (int u = 0; u < CPG; u++) {
        sc[u] = scale[c0+u] * rstd;
        bi[u] = bias[c0+u] - mu * sc[u];
    }

    const int t = ts * 1024 + threadIdx.x * 4;
    float vv[CPG][4];
    #pragma unroll
    for (int u = 0; u < CPG; u++) {
        float4 v = *(const float4*)&xp[(size_t)u * T + t];
        vv[u][0] = v.x * sc[u] + bi[u];
        vv[u][1] = v.y * sc[u] + bi[u];
        vv[u][2] = v.z * sc[u] + bi[u];
        vv[u][3] = v.w * sc[u] + bi[u];
    }
    #pragma unroll
    for (int j = 0; j < 4; j++) {
        bfv8 w = { f2bf(vv[0][j]), f2bf(vv[1][j]), f2bf(vv[2][j]), f2bf(vv[3][j]),
                   f2bf(vv[4][j]), f2bf(vv[5][j]), f2bf(vv[6][j]), f2bf(vv[7][j]) };
        *(bfv8*)&xnT[((size_t)b * T + t + j) * C + c0] = w;
    }
}

// ---------------------------------------------------------------------------
// qkv GEMM (bf16 MFMA, BK=64): grid (T/64, 12, BATCH), 256 thr.
// V store applies the PV key-permutation (swap key bits 2<->3 within each
// 16-key group) so attn's V A-fragments are 16B-contiguous in vb.
// ---------------------------------------------------------------------------
__global__ __launch_bounds__(256) void gemm_qkv(
    const short* __restrict__ wq,    // [768][256] bf16
    const float* __restrict__ bq,    // [768]
    const short* __restrict__ xnT,   // [B][T][C] bf16
    short* __restrict__ qb, short* __restrict__ kb, short* __restrict__ vb)
{
    const int b  = blockIdx.z;
    const int t0 = blockIdx.x * 64;
    const int ot = blockIdx.y;
    const int h = ot / 3, part = ot % 3;
    const int o0 = ot * 64;

    __shared__ short sm[8192];       // A 8x512 + B 8x512 shorts (16 KiB)
    short* Ab = sm;
    short* Bb = sm + 4096;

    const int tid = threadIdx.x, lane = tid & 63, wave = tid >> 6;
    const int col = lane & 15, quad = lane >> 4;
    const short* xb = xnT + (size_t)b * T * C;

    f32x4 acc[4];
    #pragma unroll
    for (int g = 0; g < 4; g++) { acc[g][0]=0.f; acc[g][1]=0.f; acc[g][2]=0.f; acc[g][3]=0.f; }

    for (int k0 = 0; k0 < C; k0 += 64) {
        __syncthreads();
        #pragma unroll
        for (int hh = 0; hh < 2; hh++) {
            gll16(wq + (size_t)(o0 + 16*wave + col) * C + k0 + hh*32 + quad*8,
                  Ab + (hh*4 + wave) * 512);
            gll16(xb + (size_t)(t0 + 16*wave + col) * C + k0 + hh*32 + quad*8,
                  Bb + (hh*4 + wave) * 512);
        }
        __syncthreads();
        #pragma unroll
        for (int hh = 0; hh < 2; hh++) {
            bfv8 af = *(const bfv8*)(Ab + (hh*4 + wave) * 512 + lane*8);
            #pragma unroll
            for (int g = 0; g < 4; g++) {
                bfv8 bf = *(const bfv8*)(Bb + (hh*4 + g) * 512 + lane*8);
                acc[g] = __builtin_amdgcn_mfma_f32_16x16x32_bf16(af, bf, acc[g], 0, 0, 0);
            }
        }
    }

    const int olocal = 16*wave + quad*4;
    float bias_r[4];
    #pragma unroll
    for (int r = 0; r < 4; r++) bias_r[r] = bq[o0 + olocal + r];
    const size_t hd = (size_t)(b * NH + h);

    if (part < 2) {
        short* dst = (part == 0 ? qb : kb) + hd * T * 64;
        const float sc = (part == 0) ? QSCALE : 1.0f;
        #pragma unroll
        for (int g = 0; g < 4; g++) {
            int t = t0 + 16*g + col;
            bfv4 w = { f2bf((acc[g][0] + bias_r[0]) * sc),
                       f2bf((acc[g][1] + bias_r[1]) * sc),
                       f2bf((acc[g][2] + bias_r[2]) * sc),
                       f2bf((acc[g][3] + bias_r[3]) * sc) };
            *(bfv4*)&dst[(size_t)t * 64 + olocal] = w;
        }
    } else {
        short* dst = vb + hd * 64 * T;
        // key-perm: swap bits 2<->3 of the within-16 key index (self-inverse)
        const int pcol = (col & 3) | ((col & 4) << 1) | ((col & 8) >> 1);
        #pragma unroll
        for (int g = 0; g < 4; g++)
            #pragma unroll
            for (int r = 0; r < 4; r++)
                dst[(size_t)(olocal + r) * T + t0 + 16*g + pcol] =
                    f2bf(acc[g][r] + bias_r[r]);
    }
}

// ---------------------------------------------------------------------------
// Flash attention v15b: fragment-major LDS layout (R7 diagnosis: kernel is
// LDS-throughput-bound with ~8-way bank conflicts from column reads; LDS
// time ~41us ~= the 46us wall). LDS chunk n holds exactly the 16B that
// read-lane (n&63) of fragment-slot (n>>6) consumes -> every read is
// base + slot*1KB + lane*16B (m134-measured conflict-free b128 pattern).
// V's kappa key-perm (swap key bits 2<->3 per 16-group) is pre-applied in
// gemm_qkv's V store, so each PV A-frag is ONE b128 (was 2x b64): LDS
// ops/wave-iter 48 -> 32, swizzle math gone.
// R8 BUG FIX: V staging column is 16*kc + 8*hi (stored-position arithmetic:
// pi maps kappa-keys {16kc+4hi+(j&3)+8(j>>2)} to positions 16kc+8hi+j);
// v15 had 32*kc + 16*hi -> slots kc>=4 read past the 128-key tile (absmax
// 0.39). Bounds now max 16*7+8+7 = 127, in-tile.
// K slots (kt,s): lane(klow,hi) <- K[32kt+klow][16s+8hi..+8].
// V slots (c,kc): lane(klow,hi) <- vbperm[32c+klow][16kc+8hi..+8].
// ---------------------------------------------------------------------------
__global__ __launch_bounds__(512, 4) void attn_kernel(
    const short* __restrict__ qb,    // [BH][T][64] (pre-scaled by QSCALE)
    const short* __restrict__ kb,    // [BH][T][64]
    const short* __restrict__ vb,    // [BH][64][T] (key-permuted, see gemm_qkv)
    short* __restrict__ opart,       // [KSPLIT][BH][T][64] unnormalized O, bf16
    float* __restrict__ lp)          // [KSPLIT][BH][T]
{
    __shared__ short smem[32768];    // 2 x (K 16KB + V 16KB) = 64 KiB
    // T1 relabel: bh = id&7 so each head's blocks share an XCD (R7: FETCH
    // 34.9 -> 6.2 MB).
    const int flat = blockIdx.x;             // 0..511
    const int bh = flat & 7;
    const int tb = (flat >> 3) & 15;
    const int ks = flat >> 7;
    const int t0 = tb * 256;
    const int k0base = ks * KRANGE;
    const short* kbh = kb + (size_t)bh * T * 64;
    const short* vbh = vb + (size_t)bh * 64 * T;

    const int tid  = threadIdx.x;
    const int lane = tid & 63;
    const int wave = tid >> 6;       // 0..7
    const int klow = lane & 31;      // m-index (key / ch) and n-index (query)
    const int hi   = lane >> 5;

    // Q B-frags: step s covers ch 16s..16s+15; slot (hi,j) -> ch 16s+8hi+j
    const int q = t0 + wave*32 + klow;
    const short* qrow = qb + (size_t)bh * T * 64 + (size_t)q * 64;
    bfv8 qf[4];
    #pragma unroll
    for (int s = 0; s < 4; s++) qf[s] = *(const bfv8*)(qrow + s*16 + hi*8);

    // O^T accumulators: tile c -> ch = 32c + (r&3)+8*(r>>2)+4hi, query = klow
    f32x16 oacc[2];
    #pragma unroll
    for (int c = 0; c < 2; c++)
        #pragma unroll
        for (int r = 0; r < 16; r++) oacc[c][r] = 0.f;
    f32x2 l2 = { 0.f, 0.f };

    // Fragment-major staging: 1024 K chunks + 1024 V chunks of 16B per
    // buffer; thread stages chunks n1 = tid and n2 = tid+512 of each.
    // K chunk n: slot g=n>>6 -> (kt=g>>2, s=g&3), lane L=n&63 ->
    //   src K[s0 + 32kt + (L&31)][16s + 8*(L>>5)]  (16B)
    // V chunk n: slot g=n>>6 -> (c=g>>3, kc=g&7), lane L=n&63 ->
    //   src vbperm[32c + (L&31)][s0 + 16kc + 8*(L>>5)]  (16B)
    const int n1 = tid, n2 = tid + 512;
    const int kOff1 = ((n1>>8)*32 + (n1&31))*64 + ((n1>>6)&3)*16 + ((n1>>5)&1)*8;
    const int kOff2 = ((n2>>8)*32 + (n2&31))*64 + ((n2>>6)&3)*16 + ((n2>>5)&1)*8;
    const size_t vRow1 = (size_t)(((n1>>9)<<5) + (n1&31)) * T;
    const size_t vRow2 = (size_t)(((n2>>9)<<5) + (n2&31)) * T;
    const int vCol1 = ((n1>>6)&7)*16 + ((n1>>5)&1)*8;
    const int vCol2 = ((n2>>6)&7)*16 + ((n2>>5)&1)*8;
    #define STAGE_KV(buf, s0)                                                   \
        {                                                                       \
            short* base = smem + (buf) * 16384;                                 \
            gll16(kbh + (size_t)(s0) * 64 + kOff1, base + n1*8);                \
            gll16(kbh + (size_t)(s0) * 64 + kOff2, base + n2*8);                \
            gll16(vbh + vRow1 + (s0) + vCol1, base + 8192 + n1*8);              \
            gll16(vbh + vRow2 + (s0) + vCol2, base + 8192 + n2*8);              \
        }

    STAGE_KV(0, k0base)

    for (int it = 0; it < NIT; it++) {
        __syncthreads();                        // staged tile visible
        if (it + 1 < NIT) STAGE_KV((it+1) & 1, k0base + (it+1)*KTILE)

        const short* kvb = smem + (it & 1) * 16384;

        // Per 32-key sub-tile kt: S^T -> exp2 -> cvt_pk pack -> PV (kc=2kt+u)
        #pragma unroll
        for (int kt = 0; kt < 4; kt++) {
            f32x16 sacc;
            #pragma unroll
            for (int r = 0; r < 16; r++) sacc[r] = 0.f;
            #pragma unroll
            for (int s = 0; s < 4; s++) {
                bfv8 kf = *(const bfv8*)(kvb + ((kt*4 + s)*64 + lane)*8);
                sacc = __builtin_amdgcn_mfma_f32_32x32x16_bf16(kf, qf[s], sacc, 0, 0, 0);
            }
            #pragma unroll
            for (int u = 0; u < 2; u++) {
                float p[8];
                #pragma unroll
                for (int j = 0; j < 8; j++) p[j] = EXP2(sacc[8*u + j]);
                f32x2 pa = { p[0], p[1] }, pb = { p[2], p[3] };
                f32x2 pc = { p[4], p[5] }, pd = { p[6], p[7] };
                l2 += (pa + pb) + (pc + pd);
                union { unsigned w[4]; bfv8 v; } pk_;
                #pragma unroll
                for (int w = 0; w < 4; w++)
                    asm("v_cvt_pk_bf16_f32 %0, %1, %2"
                        : "=v"(pk_.w[w]) : "v"(p[2*w]), "v"(p[2*w+1]));
                const int kc = 2*kt + u;    // keys kappa = 16kc+4hi+(j&3)+8*(j>>2)
                #pragma unroll
                for (int c = 0; c < 2; c++) {
                    bfv8 vf = *(const bfv8*)(kvb + 8192 + ((c*8 + kc)*64 + lane)*8);
                    oacc[c] = __builtin_amdgcn_mfma_f32_32x32x16_bf16(
                                  vf, pk_.v, oacc[c], 0, 0, 0);
                }
            }
        }
    }

    // l: lane holds 32 of the 64 keys (its hi half) for query klow
    float lsum = l2[0] + l2[1];
    lsum += __shfl_xor(lsum, 32);

    // epilogue: lane owns t-row (t0+wave*32+klow); ch = 32c + 8u + 4hi + i
    const size_t rowbase = (size_t)(ks*BH + bh) * T + t0 + wave*32;
    short* opb = opart + (rowbase + klow) * 64;
    #pragma unroll
    for (int c = 0; c < 2; c++)
        #pragma unroll
        for (int u = 0; u < 4; u++) {
            bfv4 w = { f2bf(oacc[c][4*u+0]), f2bf(oacc[c][4*u+1]),
                       f2bf(oacc[c][4*u+2]), f2bf(oacc[c][4*u+3]) };
            *(bfv4*)(opb + c*32 + u*8 + hi*4) = w;
        }
    if (hi == 0) {
        lp[rowbase + klow] = lsum;
    }
}

// ---------------------------------------------------------------------------
// proj GEMM (bf16 MFMA, BK=64) with fused combine: B-operand built from
// opart (sum KSPLIT partials x per-head rl). + bias + fp32 resid.
// grid (T/64, 4, BATCH).
// ---------------------------------------------------------------------------
__global__ __launch_bounds__(256) void gemm_proj(
    const short* __restrict__ wp,    // [256][256] bf16
    const float* __restrict__ bp,    // [256]
    const short* __restrict__ opart, // [KSPLIT][BH][T][64] bf16
    const float* __restrict__ lp,    // [KSPLIT][BH][T]
    const float* __restrict__ x,     // [B][C][T] fp32 residual
    float* __restrict__ out)         // [B][C][T] fp32
{
    const int b  = blockIdx.z;
    const int t0 = blockIdx.x * 64;
    const int o0 = blockIdx.y * 64;

    __shared__ short sm[8192];       // A 8x512 + B 8x512 shorts (16 KiB)
    short* Ab = sm;
    short* Bb = sm + 4096;

    const int tid = threadIdx.x, lane = tid & 63, wave = tid >> 6;
    const int col = lane & 15, quad = lane >> 4;

    const int trow = t0 + 16*wave + col;
    float rl4[NH];
    #pragma unroll
    for (int hh = 0; hh < NH; hh++) {
        float ls = 0.f;
        #pragma unroll
        for (int ks = 0; ks < KSPLIT; ks++)
            ls += lp[((size_t)(ks*BH) + b*NH + hh) * T + trow];
        rl4[hh] = 1.0f / ls;
    }

    f32x4 acc[4];
    #pragma unroll
    for (int g = 0; g < 4; g++) { acc[g][0]=0.f; acc[g][1]=0.f; acc[g][2]=0.f; acc[g][3]=0.f; }

    for (int k0 = 0; k0 < C; k0 += 64) {
        __syncthreads();
        #pragma unroll
        for (int hh = 0; hh < 2; hh++) {
            gll16(wp + (size_t)(o0 + 16*wave + col) * C + k0 + hh*32 + quad*8,
                  Ab + (hh*4 + wave) * 512);
            const int chg = k0 + hh*32 + quad*8;       // global channel
            const int hd = chg >> 6, chin = chg & 63;  // hd is wave-uniform
            const short* ob = opart + (((size_t)(b*NH + hd)) * T + trow) * 64 + chin;
            float a8[8] = {0.f,0.f,0.f,0.f,0.f,0.f,0.f,0.f};
            #pragma unroll
            for (int ks = 0; ks < KSPLIT; ks++) {
                bfv8 v = *(const bfv8*)(ob + (size_t)ks * BH * T * 64);
                #pragma unroll
                for (int u = 0; u < 8; u++) a8[u] += bf2f(v[u]);
            }
            const float rl = rl4[hd];
            bfv8 pk;
            #pragma unroll
            for (int u = 0; u < 8; u++) pk[u] = f2bf(a8[u] * rl);
            *(bfv8*)(Bb + (hh*4 + wave) * 512 + lane*8) = pk;
        }
        __syncthreads();
        #pragma unroll
        for (int hh = 0; hh < 2; hh++) {
            bfv8 af = *(const bfv8*)(Ab + (hh*4 + wave) * 512 + lane*8);
            #pragma unroll
            for (int g = 0; g < 4; g++) {
                bfv8 bf = *(const bfv8*)(Bb + (hh*4 + g) * 512 + lane*8);
                acc[g] = __builtin_amdgcn_mfma_f32_16x16x32_bf16(af, bf, acc[g], 0, 0, 0);
            }
        }
    }

    const int olocal = 16*wave + quad*4;
    #pragma unroll
    for (int r = 0; r < 4; r++) {
        const int o = o0 + olocal + r;
        const float bias = bp[o];
        const size_t rowoff = ((size_t)b * C + o) * T;
        #pragma unroll
        for (int g = 0; g < 4; g++) {
            const size_t idx = rowoff + t0 + 16*g + col;
            out[idx] = acc[g][r] + bias + x[idx];
        }
    }
}

// ---------------------------------------------------------------------------
extern "C" void kernel_launch(void* const* d_in, const int* in_sizes, int n_in,
                              void* d_out, int out_size, void* d_ws, size_t ws_size,
                              hipStream_t stream) {
    (void)in_sizes; (void)n_in; (void)out_size; (void)ws_size;
    const float* x        = (const float*)d_in[0];
    const float* gn_scale = (const float*)d_in[1];
    const float* gn_bias  = (const float*)d_in[2];
    const float* w_qkv    = (const float*)d_in[3];
    const float* b_qkv    = (const float*)d_in[4];
    const float* w_proj   = (const float*)d_in[5];
    const float* b_proj   = (const float*)d_in[6];
    float* out = (float*)d_out;

    short* ws    = (short*)d_ws;
    short* qb    = ws;                                  // [BH][T][64]
    short* kb    = qb  + (size_t)BH * T * 64;
    short* vb    = kb  + (size_t)BH * T * 64;
    short* xnT   = vb  + (size_t)BH * T * 64;           // [B][T][C]
    short* wqb   = xnT + (size_t)BATCH * T * C;
    short* wpb   = wqb + 768 * 256;
    short* opart = wpb + 256 * 256;                     // [KSPLIT][BH][T][64] bf16
    float* lp    = (float*)(opart + (size_t)KSPLIT * BH * T * 64);  // [KSPLIT][BH][T]
    float* gnp   = lp + (size_t)KSPLIT * BH * T;        // [64][4][2]

    prep_stats<<<dim3(512), 256, 0, stream>>>(w_qkv, w_proj, wqb, wpb, x, gnp);
    gn_norm<<<dim3(BATCH * G, 4), 256, 0, stream>>>(x, gn_scale, gn_bias, gnp, xnT);
    gemm_qkv<<<dim3(T/64, 12, BATCH), 256, 0, stream>>>(wqb, b_qkv, xnT, qb, kb, vb);
    attn_kernel<<<dim3(512), 512, 0, stream>>>(qb, kb, vb, opart, lp);
    gemm_proj<<<dim3(T/64, 4, BATCH), 256, 0, stream>>>(wpb, b_proj, opart, lp, x, out);
}